// Round 3
// baseline (8629.176 us; speedup 1.0000x reference)
//
#include <hip/hip_runtime.h>
#include <math.h>

// ---------------------------------------------------------------------------
// SequencePredictorGRU — fused persistent kernel, fp16 MFMA, fp32 accum.
// R3: occupancy 2->4 waves/SIMD. Single h buffer [64][512] f16 (64KB) + extras
// ~72KB total -> 2 blocks/CU; VGPR forced <=128 (amdgpu_waves_per_eu(4)).
// h_new held in registers (f16x4 frags) across the read/write barrier.
// G1 split into 4 quarter-passes (acc[4][3]=48 f32) to fit the register cap.
// Init t1 (64x1024) processed as two 32-row halves aliasing the h region.
// MFMA layouts (16x16x32, verified in R1/R2):
//   A: row=l&15, k=(l>>4)*8+i     B: col=l&15, k=(l>>4)*8+i
//   D: col=l&15 (-> m row), row=(l>>4)*4+r (-> j, contiguous quad)
// ---------------------------------------------------------------------------

typedef _Float16 f16;
typedef _Float16 f16x4 __attribute__((ext_vector_type(4)));
typedef _Float16 f16x8 __attribute__((ext_vector_type(8)));
typedef float f32x4 __attribute__((ext_vector_type(4)));

#define TSTEPS 20

__device__ __forceinline__ float sigm(float v) { return 1.0f / (1.0f + __expf(-v)); }
__device__ __forceinline__ float tanh_s(float v) {
  float e = __expf(-2.0f * fabsf(v));
  float r = (1.0f - e) / (1.0f + e);
  return copysignf(r, v);
}
__device__ __forceinline__ float gelu_e(float v) {
  return 0.5f * v * (1.0f + erff(v * 0.70710678118654752f));
}
__device__ __forceinline__ void st4(float* d, float4 v) {
  d[0] = v.x; d[1] = v.y; d[2] = v.z; d[3] = v.w;
}

// h region: [64][512] f16 rows of 1024 B, swizzled
__device__ __forceinline__ int haddr(int m, int k) {
  return m * 1024 + ((k * 2) ^ ((m & 7) << 4));
}
// t1 region (aliases h region): [32][1024] f16 rows of 2048 B, swizzled
__device__ __forceinline__ int taddr(int m, int c) {
  return m * 2048 + ((c * 2) ^ ((m & 7) << 4));
}

// ---------------------------------------------------------------------------
// Prologue: convert weights to fp16, K-contiguous rows.
// ---------------------------------------------------------------------------
__global__ void cvt_weights(const float* __restrict__ W1, const float* __restrict__ W2,
                            const float* __restrict__ Whh, const float* __restrict__ Wo1,
                            f16* __restrict__ w1t, f16* __restrict__ w2t,
                            f16* __restrict__ whh, f16* __restrict__ wo1t) {
  int i = blockIdx.x * 256 + threadIdx.x;
  if (i < 163840) { int n = i / 160; int k = i - n * 160; w1t[i] = (f16)W1[k * 1024 + n]; return; }
  i -= 163840;
  if (i < 524288) { int n = i >> 10; int k = i & 1023; w2t[i] = (f16)W2[k * 512 + n]; return; }
  i -= 524288;
  if (i < 786432) { whh[i] = (f16)Whh[i]; return; }
  i -= 786432;
  if (i < 131072) { int o = i >> 9; int k = i & 511; wo1t[i] = (f16)Wo1[k * 256 + o]; return; }
}

// ---------------------------------------------------------------------------
// Main fused kernel: 512 threads = 8 waves, 64 rows/block, 2 blocks/CU.
// ---------------------------------------------------------------------------
__global__ __launch_bounds__(512) __attribute__((amdgpu_waves_per_eu(4)))
void gru_main(
    const float* __restrict__ zq, const float* __restrict__ fpr,
    const float* __restrict__ b1, const float* __restrict__ g1, const float* __restrict__ be1,
    const float* __restrict__ b2, const float* __restrict__ stok,
    const float* __restrict__ Wih, const float* __restrict__ bih, const float* __restrict__ bhh,
    const float* __restrict__ bo1, const float* __restrict__ go, const float* __restrict__ beo,
    const float* __restrict__ Wo2, const float* __restrict__ bo2,
    const f16* __restrict__ w1t, const f16* __restrict__ w2t,
    const f16* __restrict__ whh, const f16* __restrict__ wo1t,
    float* __restrict__ out) {
  __shared__ __align__(16) unsigned char sm[65536];   // h[64][512] / t1[32][1024]
  __shared__ float sm_stat[64 * 9 * 2];
  __shared__ float sm_yp[64 * 9];

  const int tid = threadIdx.x;
  const int w = tid >> 6;
  const int lane = tid & 63;
  const int l16 = lane & 15;
  const int l4 = lane >> 4;
  const int R0 = blockIdx.x * 64;

  const float bo2v = bo2[0];
  float x4[4];
  {
    const float s0 = stok[0];
    #pragma unroll
    for (int mt = 0; mt < 4; ++mt) x4[mt] = s0;
  }

  // ======================= init_mlp (two 32-row halves) ====================
  f16x4 h0h[2][2][2][2];  // [half][p][jh][mt]

  #pragma unroll 1
  for (int hh = 0; hh < 2; ++hh) {
    const int RH = R0 + hh * 32;
    // ---- G0a: t1 = cat(zq,fpr) @ W1 + b1 -> t1 region ---------------------
    #pragma unroll 1
    for (int q = 0; q < 4; ++q) {
      f32x4 acc[2][2];
      #pragma unroll
      for (int mt = 0; mt < 2; ++mt)
        #pragma unroll
        for (int jh = 0; jh < 2; ++jh) acc[mt][jh] = (f32x4){0.f, 0.f, 0.f, 0.f};
      #pragma unroll
      for (int kf = 0; kf < 5; ++kf) {
        const int k0 = kf * 32 + l4 * 8;
        f16x8 B[2];
        #pragma unroll
        for (int mt = 0; mt < 2; ++mt) {
          const int gm = RH + mt * 16 + l16;
          const float* src = (kf < 4) ? (zq + gm * 128 + k0) : (fpr + gm * 32 + (k0 - 128));
          float4 v0 = *(const float4*)src;
          float4 v1 = *(const float4*)(src + 4);
          f16x8 b;
          b[0] = (f16)v0.x; b[1] = (f16)v0.y; b[2] = (f16)v0.z; b[3] = (f16)v0.w;
          b[4] = (f16)v1.x; b[5] = (f16)v1.y; b[6] = (f16)v1.z; b[7] = (f16)v1.w;
          B[mt] = b;
        }
        #pragma unroll
        for (int jh = 0; jh < 2; ++jh) {
          const f16x8 A = *(const f16x8*)(w1t + (w * 128 + q * 32 + jh * 16 + l16) * 160 + k0);
          #pragma unroll
          for (int mt = 0; mt < 2; ++mt)
            acc[mt][jh] = __builtin_amdgcn_mfma_f32_16x16x32_f16(A, B[mt], acc[mt][jh], 0, 0, 0);
        }
      }
      #pragma unroll
      for (int jh = 0; jh < 2; ++jh) {
        const int jq = w * 128 + q * 32 + jh * 16 + l4 * 4;
        float bb[4]; st4(bb, *(const float4*)(b1 + jq));
        #pragma unroll
        for (int mt = 0; mt < 2; ++mt) {
          f16x4 v;
          #pragma unroll
          for (int r = 0; r < 4; ++r) v[r] = (f16)(acc[mt][jh][r] + bb[r]);
          *(f16x4*)(sm + taddr(mt * 16 + l16, jq)) = v;
        }
      }
    }
    __syncthreads();
    // ---- LN(1024) + GELU in place (rows 32, 16 threads/row) ---------------
    {
      const int m = tid >> 4;          // 0..31
      const int c0 = (tid & 15) * 64;  // 64-col strip
      float s = 0.f, ss = 0.f;
      #pragma unroll
      for (int cb = 0; cb < 8; ++cb) {
        f16x8 v = *(const f16x8*)(sm + taddr(m, c0 + cb * 8));
        #pragma unroll
        for (int i = 0; i < 8; ++i) { float f = (float)v[i]; s += f; ss += f * f; }
      }
      s += __shfl_xor(s, 1); ss += __shfl_xor(ss, 1);
      s += __shfl_xor(s, 2); ss += __shfl_xor(ss, 2);
      s += __shfl_xor(s, 4); ss += __shfl_xor(ss, 4);
      s += __shfl_xor(s, 8); ss += __shfl_xor(ss, 8);
      const float mean = s * (1.f / 1024.f);
      const float rstd = rsqrtf(ss * (1.f / 1024.f) - mean * mean + 1e-5f);
      #pragma unroll 2
      for (int cb = 0; cb < 8; ++cb) {
        const int c = c0 + cb * 8;
        f16x8 v = *(const f16x8*)(sm + taddr(m, c));
        float4 ga = *(const float4*)(g1 + c);
        float4 gb = *(const float4*)(g1 + c + 4);
        float4 ba = *(const float4*)(be1 + c);
        float4 bb = *(const float4*)(be1 + c + 4);
        float gs[8] = {ga.x, ga.y, ga.z, ga.w, gb.x, gb.y, gb.z, gb.w};
        float bs[8] = {ba.x, ba.y, ba.z, ba.w, bb.x, bb.y, bb.z, bb.w};
        f16x8 o;
        #pragma unroll
        for (int i = 0; i < 8; ++i)
          o[i] = (f16)gelu_e(((float)v[i] - mean) * rstd * gs[i] + bs[i]);
        *(f16x8*)(sm + taddr(m, c)) = o;
      }
    }
    __syncthreads();
    // ---- G0b: h0_half = tanh(t1g @ W2 + b2) -> regs -----------------------
    #pragma unroll 1
    for (int p = 0; p < 2; ++p) {
      f32x4 acc[2][2];
      #pragma unroll
      for (int mt = 0; mt < 2; ++mt)
        #pragma unroll
        for (int jh = 0; jh < 2; ++jh) acc[mt][jh] = (f32x4){0.f, 0.f, 0.f, 0.f};
      #pragma unroll 2
      for (int kf = 0; kf < 32; ++kf) {
        const int k0 = kf * 32 + l4 * 8;
        f16x8 B[2];
        #pragma unroll
        for (int mt = 0; mt < 2; ++mt)
          B[mt] = *(const f16x8*)(sm + taddr(mt * 16 + l16, k0));
        #pragma unroll
        for (int jh = 0; jh < 2; ++jh) {
          const f16x8 A = *(const f16x8*)(w2t + (w * 64 + p * 32 + jh * 16 + l16) * 1024 + k0);
          #pragma unroll
          for (int mt = 0; mt < 2; ++mt)
            acc[mt][jh] = __builtin_amdgcn_mfma_f32_16x16x32_f16(A, B[mt], acc[mt][jh], 0, 0, 0);
        }
      }
      #pragma unroll
      for (int jh = 0; jh < 2; ++jh) {
        const int jq = w * 64 + p * 32 + jh * 16 + l4 * 4;
        float bb[4]; st4(bb, *(const float4*)(b2 + jq));
        #pragma unroll
        for (int mt = 0; mt < 2; ++mt) {
          f16x4 v;
          #pragma unroll
          for (int r = 0; r < 4; ++r) v[r] = (f16)tanh_s(acc[mt][jh][r] + bb[r]);
          h0h[hh][p][jh][mt] = v;
        }
      }
    }
    __syncthreads();  // t1 reads done; region reusable
  }
  // ---- commit h0 ----------------------------------------------------------
  #pragma unroll
  for (int hh = 0; hh < 2; ++hh)
    #pragma unroll
    for (int p = 0; p < 2; ++p)
      #pragma unroll
      for (int jh = 0; jh < 2; ++jh) {
        const int k = w * 64 + p * 32 + jh * 16 + l4 * 4;
        #pragma unroll
        for (int mt = 0; mt < 2; ++mt)
          *(f16x4*)(sm + haddr(hh * 32 + mt * 16 + l16, k)) = h0h[hh][p][jh][mt];
      }
  __syncthreads();

  // ============================ GRU loop ===================================
  #pragma unroll 1
  for (int t = 0; t < TSTEPS; ++t) {
    // ---- G1: gates = Whh · h^T, blend -> hnh regs -------------------------
    f16x4 hnh[4][4];  // [q][mt]
    #pragma unroll 1
    for (int q = 0; q < 4; ++q) {
      const int jt = w * 64 + q * 16;
      f32x4 acc[4][3];
      #pragma unroll
      for (int mt = 0; mt < 4; ++mt)
        #pragma unroll
        for (int g = 0; g < 3; ++g) acc[mt][g] = (f32x4){0.f, 0.f, 0.f, 0.f};
      #pragma unroll 2
      for (int kf = 0; kf < 16; ++kf) {
        const int k0 = kf * 32 + l4 * 8;
        f16x8 B[4];
        #pragma unroll
        for (int mt = 0; mt < 4; ++mt)
          B[mt] = *(const f16x8*)(sm + haddr(mt * 16 + l16, k0));
        #pragma unroll
        for (int g = 0; g < 3; ++g) {
          const f16x8 A = *(const f16x8*)(whh + (g * 512 + jt + l16) * 512 + k0);
          #pragma unroll
          for (int mt = 0; mt < 4; ++mt)
            acc[mt][g] = __builtin_amdgcn_mfma_f32_16x16x32_f16(A, B[mt], acc[mt][g], 0, 0, 0);
        }
      }
      const int jq = jt + l4 * 4;
      float wr[4], wz[4], wn[4], br[4], bz[4], bn[4], cr[4], cz[4], cn[4];
      st4(wr, *(const float4*)(Wih + jq));
      st4(wz, *(const float4*)(Wih + 512 + jq));
      st4(wn, *(const float4*)(Wih + 1024 + jq));
      st4(br, *(const float4*)(bih + jq));
      st4(bz, *(const float4*)(bih + 512 + jq));
      st4(bn, *(const float4*)(bih + 1024 + jq));
      st4(cr, *(const float4*)(bhh + jq));
      st4(cz, *(const float4*)(bhh + 512 + jq));
      st4(cn, *(const float4*)(bhh + 1024 + jq));
      #pragma unroll
      for (int mt = 0; mt < 4; ++mt) {
        const int m = mt * 16 + l16;
        const float x = x4[mt];
        const f16x4 ho = *(const f16x4*)(sm + haddr(m, jq));
        f16x4 hn;
        #pragma unroll
        for (int r = 0; r < 4; ++r) {
          const float gr = sigm(x * wr[r] + br[r] + acc[mt][0][r] + cr[r]);
          const float gz = sigm(x * wz[r] + bz[r] + acc[mt][1][r] + cz[r]);
          const float gn = tanh_s(x * wn[r] + bn[r] + gr * (acc[mt][2][r] + cn[r]));
          hn[r] = (f16)((1.f - gz) * gn + gz * (float)ho[r]);
        }
        hnh[q][mt] = hn;
      }
    }
    __syncthreads();  // B1: all h reads done
    #pragma unroll
    for (int q = 0; q < 4; ++q) {
      const int jq = w * 64 + q * 16 + l4 * 4;
      #pragma unroll
      for (int mt = 0; mt < 4; ++mt)
        *(f16x4*)(sm + haddr(mt * 16 + l16, jq)) = hnh[q][mt];
    }
    __syncthreads();  // B2: h_new committed
    // ---- G2: y = gelu(LN(h_new @ Wo1 + bo1)) @ Wo2 + bo2 ------------------
    {
      f32x4 a2[4][2];
      #pragma unroll
      for (int mt = 0; mt < 4; ++mt)
        #pragma unroll
        for (int jt2 = 0; jt2 < 2; ++jt2) a2[mt][jt2] = (f32x4){0.f, 0.f, 0.f, 0.f};
      #pragma unroll 2
      for (int kf = 0; kf < 16; ++kf) {
        const int k0 = kf * 32 + l4 * 8;
        f16x8 B[4];
        #pragma unroll
        for (int mt = 0; mt < 4; ++mt)
          B[mt] = *(const f16x8*)(sm + haddr(mt * 16 + l16, k0));
        #pragma unroll
        for (int jt2 = 0; jt2 < 2; ++jt2) {
          const f16x8 A = *(const f16x8*)(wo1t + (w * 32 + jt2 * 16 + l16) * 512 + k0);
          #pragma unroll
          for (int mt = 0; mt < 4; ++mt)
            a2[mt][jt2] = __builtin_amdgcn_mfma_f32_16x16x32_f16(A, B[mt], a2[mt][jt2], 0, 0, 0);
        }
      }
      float vv[4][2][4];
      float bo1v[2][4];
      #pragma unroll
      for (int jt2 = 0; jt2 < 2; ++jt2)
        st4(bo1v[jt2], *(const float4*)(bo1 + w * 32 + jt2 * 16 + l4 * 4));
      #pragma unroll
      for (int mt = 0; mt < 4; ++mt) {
        float s = 0.f, ss = 0.f;
        #pragma unroll
        for (int jt2 = 0; jt2 < 2; ++jt2)
          #pragma unroll
          for (int r = 0; r < 4; ++r) {
            const float v = a2[mt][jt2][r] + bo1v[jt2][r];
            vv[mt][jt2][r] = v; s += v; ss += v * v;
          }
        s += __shfl_xor(s, 16); ss += __shfl_xor(ss, 16);
        s += __shfl_xor(s, 32); ss += __shfl_xor(ss, 32);
        if (l4 == 0) {
          const int m = mt * 16 + l16;
          sm_stat[(m * 9 + w) * 2] = s;
          sm_stat[(m * 9 + w) * 2 + 1] = ss;
        }
      }
      __syncthreads();  // B3: stats visible
      float gov[2][4], bev[2][4], wv[2][4];
      #pragma unroll
      for (int jt2 = 0; jt2 < 2; ++jt2) {
        const int jb = w * 32 + jt2 * 16 + l4 * 4;
        st4(gov[jt2], *(const float4*)(go + jb));
        st4(bev[jt2], *(const float4*)(beo + jb));
        st4(wv[jt2], *(const float4*)(Wo2 + jb));
      }
      #pragma unroll
      for (int mt = 0; mt < 4; ++mt) {
        const int m = mt * 16 + l16;
        float s = 0.f, ss = 0.f;
        #pragma unroll
        for (int i = 0; i < 8; ++i) {
          s += sm_stat[(m * 9 + i) * 2];
          ss += sm_stat[(m * 9 + i) * 2 + 1];
        }
        const float mean = s * (1.f / 256.f);
        const float rstd = rsqrtf(ss * (1.f / 256.f) - mean * mean + 1e-5f);
        float y = 0.f;
        #pragma unroll
        for (int jt2 = 0; jt2 < 2; ++jt2)
          #pragma unroll
          for (int r = 0; r < 4; ++r)
            y += gelu_e((vv[mt][jt2][r] - mean) * rstd * gov[jt2][r] + bev[jt2][r]) * wv[jt2][r];
        y += __shfl_xor(y, 16);
        y += __shfl_xor(y, 32);
        if (l4 == 0) sm_yp[m * 9 + w] = y;
      }
      __syncthreads();  // B4: y partials visible
      #pragma unroll
      for (int mt = 0; mt < 4; ++mt) {
        const int m = mt * 16 + l16;
        float ys = bo2v;
        #pragma unroll
        for (int i = 0; i < 8; ++i) ys += sm_yp[m * 9 + i];
        x4[mt] = ys;
        if (w == 0 && l4 == 0) out[(R0 + m) * 20 + t] = ys;
      }
    }
  }
}

// ---------------------------------------------------------------------------
extern "C" void kernel_launch(void* const* d_in, const int* in_sizes, int n_in,
                              void* d_out, int out_size, void* d_ws, size_t ws_size,
                              hipStream_t stream) {
  const float* zq   = (const float*)d_in[0];
  const float* fpr  = (const float*)d_in[1];
  const float* W1   = (const float*)d_in[2];
  const float* b1   = (const float*)d_in[3];
  const float* g1   = (const float*)d_in[4];
  const float* be1  = (const float*)d_in[5];
  const float* W2   = (const float*)d_in[6];
  const float* b2   = (const float*)d_in[7];
  const float* stok = (const float*)d_in[8];
  const float* Wih  = (const float*)d_in[9];
  const float* Whh  = (const float*)d_in[10];
  const float* bih  = (const float*)d_in[11];
  const float* bhh  = (const float*)d_in[12];
  const float* Wo1  = (const float*)d_in[13];
  const float* bo1  = (const float*)d_in[14];
  const float* go   = (const float*)d_in[15];
  const float* beo  = (const float*)d_in[16];
  const float* Wo2  = (const float*)d_in[17];
  const float* bo2  = (const float*)d_in[18];

  char* ws = (char*)d_ws;
  f16* w1t  = (f16*)(ws + 0);        // 1024*160*2  = 327680
  f16* w2t  = (f16*)(ws + 327680);   // 512*1024*2  = 1048576
  f16* whh  = (f16*)(ws + 1376256);  // 1536*512*2  = 1572864
  f16* wo1t = (f16*)(ws + 2949120);  // 256*512*2   = 262144  (total ~3.1MB)

  cvt_weights<<<6272, 256, 0, stream>>>(W1, W2, Whh, Wo1, w1t, w2t, whh, wo1t);

  const int N = in_sizes[0] / 128;  // 65536 rows
  gru_main<<<N / 64, 512, 0, stream>>>(zq, fpr, b1, g1, be1, b2, stok, Wih, bih, bhh,
                                       bo1, go, beo, Wo2, bo2, w1t, w2t, whh, wo1t,
                                       (float*)d_out);
}

// Round 5
// 5250.135 us; speedup vs baseline: 1.6436x; 1.6436x over previous
//
#include <hip/hip_runtime.h>
#include <math.h>

// ---------------------------------------------------------------------------
// SequencePredictorGRU — fused persistent kernel, fp16 MFMA, fp32 accum.
// R4b: (R4 with compile fix) 1024-thread block (16 waves), 64 rows/block,
// double-buffered h in LDS (2 x 64KB). 4 waves/SIMD pinned via
// amdgpu_waves_per_eu(4,4) -> 128 VGPRs. h_new writes go directly to the
// other buffer (no register holding, no WAR barrier). Per-wave j-slice = 32
// cols (2 passes of 16), acc[4mt][3g]=48 f32. Gate biases pre-summed
// (bih+bhh for r,z) in cvt_weights to cut blend register pressure.
// 4 barriers/step, one overlapped with q0's MFMA loop.
// MFMA layouts (16x16x32, verified R1-R3):
//   A: row=l&15, k=(l>>4)*8+i     B: col=l&15, k=(l>>4)*8+i
//   D: col=l&15 (-> m row), row=(l>>4)*4+r (-> j, contiguous quad)
// ---------------------------------------------------------------------------

typedef _Float16 f16;
typedef _Float16 f16x4 __attribute__((ext_vector_type(4)));
typedef _Float16 f16x8 __attribute__((ext_vector_type(8)));
typedef float f32x4 __attribute__((ext_vector_type(4)));

#define TSTEPS 20

__device__ __forceinline__ float sigm(float v) { return 1.0f / (1.0f + __expf(-v)); }
__device__ __forceinline__ float tanh_s(float v) {
  float e = __expf(-2.0f * fabsf(v));
  float r = (1.0f - e) / (1.0f + e);
  return copysignf(r, v);
}
__device__ __forceinline__ float gelu_e(float v) {
  return 0.5f * v * (1.0f + erff(v * 0.70710678118654752f));
}
__device__ __forceinline__ void st4(float* d, float4 v) {
  d[0] = v.x; d[1] = v.y; d[2] = v.z; d[3] = v.w;
}

// h buffer: buf (0 or 65536) + [64][512] f16 rows of 1024 B, swizzled
__device__ __forceinline__ int haddr(int buf, int m, int k) {
  return buf + m * 1024 + ((k * 2) ^ ((m & 7) << 4));
}
// t1 region (aliases both h buffers): [64][1024] f16 rows of 2048 B, swizzled
__device__ __forceinline__ int taddr(int m, int c) {
  return m * 2048 + ((c * 2) ^ ((m & 7) << 4));
}

// ---------------------------------------------------------------------------
// Prologue: fp16 weights (K-contiguous) + pre-summed gate biases.
// ---------------------------------------------------------------------------
__global__ void cvt_weights(const float* __restrict__ W1, const float* __restrict__ W2,
                            const float* __restrict__ Whh, const float* __restrict__ Wo1,
                            const float* __restrict__ bih, const float* __restrict__ bhh,
                            f16* __restrict__ w1t, f16* __restrict__ w2t,
                            f16* __restrict__ whh, f16* __restrict__ wo1t,
                            float* __restrict__ bcr, float* __restrict__ bcz) {
  int i = blockIdx.x * 256 + threadIdx.x;
  if (i < 163840) { int n = i / 160; int k = i - n * 160; w1t[i] = (f16)W1[k * 1024 + n]; return; }
  i -= 163840;
  if (i < 524288) { int n = i >> 10; int k = i & 1023; w2t[i] = (f16)W2[k * 512 + n]; return; }
  i -= 524288;
  if (i < 786432) { whh[i] = (f16)Whh[i]; return; }
  i -= 786432;
  if (i < 131072) { int o = i >> 9; int k = i & 511; wo1t[i] = (f16)Wo1[k * 256 + o]; return; }
  i -= 131072;
  if (i < 512) { bcr[i] = bih[i] + bhh[i]; return; }
  i -= 512;
  if (i < 512) { bcz[i] = bih[512 + i] + bhh[512 + i]; return; }
}

// ---------------------------------------------------------------------------
// Main fused kernel: 1024 threads = 16 waves, 64 rows/block, 1 block/CU.
// ---------------------------------------------------------------------------
__global__ __launch_bounds__(1024) __attribute__((amdgpu_waves_per_eu(4, 4)))
void gru_main(
    const float* __restrict__ zq, const float* __restrict__ fpr,
    const float* __restrict__ b1, const float* __restrict__ g1, const float* __restrict__ be1,
    const float* __restrict__ b2, const float* __restrict__ stok,
    const float* __restrict__ Wih, const float* __restrict__ bih, const float* __restrict__ bhh,
    const float* __restrict__ bo1, const float* __restrict__ go, const float* __restrict__ beo,
    const float* __restrict__ Wo2, const float* __restrict__ bo2,
    const f16* __restrict__ w1t, const f16* __restrict__ w2t,
    const f16* __restrict__ whh, const f16* __restrict__ wo1t,
    const float* __restrict__ bcr, const float* __restrict__ bcz,
    float* __restrict__ out) {
  __shared__ __align__(16) unsigned char sm[131072];  // h dbuf 2x[64][512] / t1[64][1024]
  __shared__ float sm_s[64 * 20], sm_ss[64 * 20], sm_yp[64 * 20];
  __shared__ float sm_x[64];

  const int tid = threadIdx.x;
  const int w = tid >> 6;        // 0..15
  const int lane = tid & 63;
  const int l16 = lane & 15;
  const int l4 = lane >> 4;
  const int R0 = blockIdx.x * 64;

  const float bo2v = bo2[0];
  if (tid < 64) sm_x[tid] = stok[0];

  // ================= G0a: t1 = cat(zq,fpr) @ W1 + b1 ======================
  #pragma unroll 1
  for (int q = 0; q < 4; ++q) {
    f32x4 acc[4];
    #pragma unroll
    for (int mt = 0; mt < 4; ++mt) acc[mt] = (f32x4){0.f, 0.f, 0.f, 0.f};
    #pragma unroll
    for (int kf = 0; kf < 5; ++kf) {
      const int k0 = kf * 32 + l4 * 8;
      f16x8 B[4];
      #pragma unroll
      for (int mt = 0; mt < 4; ++mt) {
        const int gm = R0 + mt * 16 + l16;
        const float* src = (kf < 4) ? (zq + gm * 128 + k0) : (fpr + gm * 32 + (k0 - 128));
        float4 v0 = *(const float4*)src;
        float4 v1 = *(const float4*)(src + 4);
        f16x8 b;
        b[0] = (f16)v0.x; b[1] = (f16)v0.y; b[2] = (f16)v0.z; b[3] = (f16)v0.w;
        b[4] = (f16)v1.x; b[5] = (f16)v1.y; b[6] = (f16)v1.z; b[7] = (f16)v1.w;
        B[mt] = b;
      }
      const f16x8 A = *(const f16x8*)(w1t + (w * 64 + q * 16 + l16) * 160 + k0);
      #pragma unroll
      for (int mt = 0; mt < 4; ++mt)
        acc[mt] = __builtin_amdgcn_mfma_f32_16x16x32_f16(A, B[mt], acc[mt], 0, 0, 0);
    }
    const int jq = w * 64 + q * 16 + l4 * 4;
    float bb[4]; st4(bb, *(const float4*)(b1 + jq));
    #pragma unroll
    for (int mt = 0; mt < 4; ++mt) {
      f16x4 v;
      #pragma unroll
      for (int r = 0; r < 4; ++r) v[r] = (f16)(acc[mt][r] + bb[r]);
      *(f16x4*)(sm + taddr(mt * 16 + l16, jq)) = v;
    }
  }
  __syncthreads();
  // ================= LN(1024) + GELU in place ==============================
  {
    const int m = tid >> 4;          // 0..63
    const int c0 = (tid & 15) * 64;  // 64-col strip
    float s = 0.f, ss = 0.f;
    #pragma unroll
    for (int cb = 0; cb < 8; ++cb) {
      f16x8 v = *(const f16x8*)(sm + taddr(m, c0 + cb * 8));
      #pragma unroll
      for (int i = 0; i < 8; ++i) { float f = (float)v[i]; s += f; ss += f * f; }
    }
    s += __shfl_xor(s, 1); ss += __shfl_xor(ss, 1);
    s += __shfl_xor(s, 2); ss += __shfl_xor(ss, 2);
    s += __shfl_xor(s, 4); ss += __shfl_xor(ss, 4);
    s += __shfl_xor(s, 8); ss += __shfl_xor(ss, 8);
    const float mean = s * (1.f / 1024.f);
    const float rstd = rsqrtf(ss * (1.f / 1024.f) - mean * mean + 1e-5f);
    #pragma unroll 2
    for (int cb = 0; cb < 8; ++cb) {
      const int c = c0 + cb * 8;
      f16x8 v = *(const f16x8*)(sm + taddr(m, c));
      float4 ga = *(const float4*)(g1 + c);
      float4 gb = *(const float4*)(g1 + c + 4);
      float4 ba = *(const float4*)(be1 + c);
      float4 bb = *(const float4*)(be1 + c + 4);
      float gs[8] = {ga.x, ga.y, ga.z, ga.w, gb.x, gb.y, gb.z, gb.w};
      float bs[8] = {ba.x, ba.y, ba.z, ba.w, bb.x, bb.y, bb.z, bb.w};
      f16x8 o;
      #pragma unroll
      for (int i = 0; i < 8; ++i)
        o[i] = (f16)gelu_e(((float)v[i] - mean) * rstd * gs[i] + bs[i]);
      *(f16x8*)(sm + taddr(m, c)) = o;
    }
  }
  __syncthreads();
  // ================= G0b: h0 = tanh(t1g @ W2 + b2) -> regs =================
  f16x4 h0[2][4];
  #pragma unroll 1
  for (int jh = 0; jh < 2; ++jh) {
    f32x4 acc[4];
    #pragma unroll
    for (int mt = 0; mt < 4; ++mt) acc[mt] = (f32x4){0.f, 0.f, 0.f, 0.f};
    #pragma unroll 2
    for (int kf = 0; kf < 32; ++kf) {
      const int k0 = kf * 32 + l4 * 8;
      f16x8 B[4];
      #pragma unroll
      for (int mt = 0; mt < 4; ++mt)
        B[mt] = *(const f16x8*)(sm + taddr(mt * 16 + l16, k0));
      const f16x8 A = *(const f16x8*)(w2t + (w * 32 + jh * 16 + l16) * 1024 + k0);
      #pragma unroll
      for (int mt = 0; mt < 4; ++mt)
        acc[mt] = __builtin_amdgcn_mfma_f32_16x16x32_f16(A, B[mt], acc[mt], 0, 0, 0);
    }
    const int jq = w * 32 + jh * 16 + l4 * 4;
    float bb[4]; st4(bb, *(const float4*)(b2 + jq));
    #pragma unroll
    for (int mt = 0; mt < 4; ++mt) {
      f16x4 v;
      #pragma unroll
      for (int r = 0; r < 4; ++r) v[r] = (f16)tanh_s(acc[mt][r] + bb[r]);
      h0[jh][mt] = v;
    }
  }
  __syncthreads();  // all t1 reads done; region reusable as h buffers
  #pragma unroll
  for (int jh = 0; jh < 2; ++jh) {
    const int jq = w * 32 + jh * 16 + l4 * 4;
    #pragma unroll
    for (int mt = 0; mt < 4; ++mt)
      *(f16x4*)(sm + haddr(0, mt * 16 + l16, jq)) = h0[jh][mt];
  }
  __syncthreads();

  // ============================ GRU loop ===================================
  #pragma unroll 1
  for (int t = 0; t < TSTEPS; ++t) {
    const int cur = (t & 1) << 16;
    const int nxt = cur ^ 65536;
    // ---- G1: gates = Whh · h^T, blend -> h[nxt] directly ------------------
    #pragma unroll 1
    for (int q = 0; q < 2; ++q) {
      const int jt = w * 32 + q * 16;
      f32x4 acc[4][3];
      #pragma unroll
      for (int mt = 0; mt < 4; ++mt)
        #pragma unroll
        for (int g = 0; g < 3; ++g) acc[mt][g] = (f32x4){0.f, 0.f, 0.f, 0.f};
      #pragma unroll 2
      for (int kf = 0; kf < 16; ++kf) {
        const int k0 = kf * 32 + l4 * 8;
        f16x8 B[4];
        #pragma unroll
        for (int mt = 0; mt < 4; ++mt)
          B[mt] = *(const f16x8*)(sm + haddr(cur, mt * 16 + l16, k0));
        #pragma unroll
        for (int g = 0; g < 3; ++g) {
          const f16x8 A = *(const f16x8*)(whh + (g * 512 + jt + l16) * 512 + k0);
          #pragma unroll
          for (int mt = 0; mt < 4; ++mt)
            acc[mt][g] = __builtin_amdgcn_mfma_f32_16x16x32_f16(A, B[mt], acc[mt][g], 0, 0, 0);
        }
      }
      if (q == 0) __syncthreads();  // B5: sm_x(t) visible (hidden behind q0 MFMA)
      const int jq = jt + l4 * 4;
      float wr[4], wz[4], wn[4], cr[4], cz[4], bn[4], cn[4];
      st4(wr, *(const float4*)(Wih + jq));
      st4(wz, *(const float4*)(Wih + 512 + jq));
      st4(wn, *(const float4*)(Wih + 1024 + jq));
      st4(cr, *(const float4*)(bcr + jq));
      st4(cz, *(const float4*)(bcz + jq));
      st4(bn, *(const float4*)(bih + 1024 + jq));
      st4(cn, *(const float4*)(bhh + 1024 + jq));
      #pragma unroll
      for (int mt = 0; mt < 4; ++mt) {
        const int m = mt * 16 + l16;
        const float x = sm_x[m];
        const int hoff = m * 1024 + ((jq * 2) ^ ((m & 7) << 4));
        const f16x4 ho = *(const f16x4*)(sm + cur + hoff);
        f16x4 hn;
        #pragma unroll
        for (int r = 0; r < 4; ++r) {
          const float gr = sigm(x * wr[r] + cr[r] + acc[mt][0][r]);
          const float gz = sigm(x * wz[r] + cz[r] + acc[mt][1][r]);
          const float gn = tanh_s(x * wn[r] + bn[r] + gr * (acc[mt][2][r] + cn[r]));
          hn[r] = (f16)((1.f - gz) * gn + gz * (float)ho[r]);
        }
        *(f16x4*)(sm + nxt + hoff) = hn;
      }
    }
    __syncthreads();  // B2: h[nxt] complete
    // ---- G2: y = gelu(LN(h_new @ Wo1 + bo1)) @ Wo2 + bo2 ------------------
    {
      f32x4 a2[4];
      #pragma unroll
      for (int mt = 0; mt < 4; ++mt) a2[mt] = (f32x4){0.f, 0.f, 0.f, 0.f};
      #pragma unroll 2
      for (int kf = 0; kf < 16; ++kf) {
        const int k0 = kf * 32 + l4 * 8;
        f16x8 B[4];
        #pragma unroll
        for (int mt = 0; mt < 4; ++mt)
          B[mt] = *(const f16x8*)(sm + haddr(nxt, mt * 16 + l16, k0));
        const f16x8 A = *(const f16x8*)(wo1t + (w * 16 + l16) * 512 + k0);
        #pragma unroll
        for (int mt = 0; mt < 4; ++mt)
          a2[mt] = __builtin_amdgcn_mfma_f32_16x16x32_f16(A, B[mt], a2[mt], 0, 0, 0);
      }
      const int c4 = w * 16 + l4 * 4;
      float vv[4][4];
      float bo1v[4]; st4(bo1v, *(const float4*)(bo1 + c4));
      #pragma unroll
      for (int mt = 0; mt < 4; ++mt) {
        float s = 0.f, ss = 0.f;
        #pragma unroll
        for (int r = 0; r < 4; ++r) {
          const float v = a2[mt][r] + bo1v[r];
          vv[mt][r] = v; s += v; ss += v * v;
        }
        s += __shfl_xor(s, 16); ss += __shfl_xor(ss, 16);
        s += __shfl_xor(s, 32); ss += __shfl_xor(ss, 32);
        if (l4 == 0) {
          const int m = mt * 16 + l16;
          sm_s[m * 20 + w] = s;
          sm_ss[m * 20 + w] = ss;
        }
      }
      __syncthreads();  // B3: stats partials visible
      float gov[4], bev[4], wv[4];
      st4(gov, *(const float4*)(go + c4));
      st4(bev, *(const float4*)(beo + c4));
      st4(wv, *(const float4*)(Wo2 + c4));
      #pragma unroll
      for (int mt = 0; mt < 4; ++mt) {
        const int m = mt * 16 + l16;
        float s = 0.f, ss = 0.f;
        #pragma unroll
        for (int i = 0; i < 4; ++i) {
          float4 ps = *(const float4*)(sm_s + m * 20 + i * 4);
          float4 pq = *(const float4*)(sm_ss + m * 20 + i * 4);
          s += ps.x + ps.y + ps.z + ps.w;
          ss += pq.x + pq.y + pq.z + pq.w;
        }
        const float mean = s * (1.f / 256.f);
        const float rstd = rsqrtf(ss * (1.f / 256.f) - mean * mean + 1e-5f);
        float y = 0.f;
        #pragma unroll
        for (int r = 0; r < 4; ++r)
          y += gelu_e((vv[mt][r] - mean) * rstd * gov[r] + bev[r]) * wv[r];
        y += __shfl_xor(y, 16);
        y += __shfl_xor(y, 32);
        if (l4 == 0) sm_yp[m * 20 + w] = y;
      }
      __syncthreads();  // B4: y partials visible
      if (tid < 64) {
        const int m = tid;
        float y = bo2v;
        #pragma unroll
        for (int i = 0; i < 4; ++i) {
          float4 ps = *(const float4*)(sm_yp + m * 20 + i * 4);
          y += ps.x + ps.y + ps.z + ps.w;
        }
        sm_x[m] = y;
        out[(R0 + m) * 20 + t] = y;
      }
      // no trailing barrier: next step's B5 (inside q0) covers sm_x visibility
    }
  }
}

// ---------------------------------------------------------------------------
extern "C" void kernel_launch(void* const* d_in, const int* in_sizes, int n_in,
                              void* d_out, int out_size, void* d_ws, size_t ws_size,
                              hipStream_t stream) {
  const float* zq   = (const float*)d_in[0];
  const float* fpr  = (const float*)d_in[1];
  const float* W1   = (const float*)d_in[2];
  const float* b1   = (const float*)d_in[3];
  const float* g1   = (const float*)d_in[4];
  const float* be1  = (const float*)d_in[5];
  const float* W2   = (const float*)d_in[6];
  const float* b2   = (const float*)d_in[7];
  const float* stok = (const float*)d_in[8];
  const float* Wih  = (const float*)d_in[9];
  const float* Whh  = (const float*)d_in[10];
  const float* bih  = (const float*)d_in[11];
  const float* bhh  = (const float*)d_in[12];
  const float* Wo1  = (const float*)d_in[13];
  const float* bo1  = (const float*)d_in[14];
  const float* go   = (const float*)d_in[15];
  const float* beo  = (const float*)d_in[16];
  const float* Wo2  = (const float*)d_in[17];
  const float* bo2  = (const float*)d_in[18];

  char* ws = (char*)d_ws;
  f16* w1t   = (f16*)(ws + 0);        // 1024*160*2  = 327680
  f16* w2t   = (f16*)(ws + 327680);   // 512*1024*2  = 1048576
  f16* whh   = (f16*)(ws + 1376256);  // 1536*512*2  = 1572864
  f16* wo1t  = (f16*)(ws + 2949120);  // 256*512*2   = 262144
  float* bcr = (float*)(ws + 3211264);  // 512*4 = 2048
  float* bcz = (float*)(ws + 3213312);  // 512*4 = 2048  (total ~3.2MB)

  cvt_weights<<<6276, 256, 0, stream>>>(W1, W2, Whh, Wo1, bih, bhh,
                                        w1t, w2t, whh, wo1t, bcr, bcz);

  const int N = in_sizes[0] / 128;  // 65536 rows
  gru_main<<<N / 64, 1024, 0, stream>>>(zq, fpr, b1, g1, be1, b2, stok, Wih, bih, bhh,
                                        bo1, go, beo, Wo2, bo2, w1t, w2t, whh, wo1t,
                                        bcr, bcz, (float*)d_out);
}

// Round 6
// 5214.960 us; speedup vs baseline: 1.6547x; 1.0067x over previous
//
#include <hip/hip_runtime.h>
#include <math.h>

// ---------------------------------------------------------------------------
// SequencePredictorGRU — fused persistent kernel, fp16 MFMA, fp32 accum.
// R6: R4b with the register pin FIXED. Evidence across R1/R2/R3/R5: hipcc's
// allocator budgets VGPR = 512/(2*min_waves_per_eu); amdgpu_waves_per_eu max
// is ignored. So declare __launch_bounds__(1024, 2) -> 128 VGPR budget.
// Actual occupancy stays 1 block/CU (LDS 143KB) = 4 waves/SIMD.
// Structure: 1024 threads (16 waves), 64 rows/block, double-buffered h in LDS
// (2 x 64KB); h_new written straight to the other buffer (no hold regs).
// G1 per wave: j-slice 32 (2 passes of 16), acc[4mt][3g] = 48 f32 regs.
// MFMA layouts (16x16x32, verified R1-R5):
//   A: row=l&15, k=(l>>4)*8+i     B: col=l&15, k=(l>>4)*8+i
//   D: col=l&15 (-> m row), row=(l>>4)*4+r (-> j, contiguous quad)
// ---------------------------------------------------------------------------

typedef _Float16 f16;
typedef _Float16 f16x4 __attribute__((ext_vector_type(4)));
typedef _Float16 f16x8 __attribute__((ext_vector_type(8)));
typedef float f32x4 __attribute__((ext_vector_type(4)));

#define TSTEPS 20

__device__ __forceinline__ float sigm(float v) { return 1.0f / (1.0f + __expf(-v)); }
__device__ __forceinline__ float tanh_s(float v) {
  float e = __expf(-2.0f * fabsf(v));
  float r = (1.0f - e) / (1.0f + e);
  return copysignf(r, v);
}
__device__ __forceinline__ float gelu_e(float v) {
  return 0.5f * v * (1.0f + erff(v * 0.70710678118654752f));
}
__device__ __forceinline__ void st4(float* d, float4 v) {
  d[0] = v.x; d[1] = v.y; d[2] = v.z; d[3] = v.w;
}

// h buffer: buf (0 or 65536) + [64][512] f16 rows of 1024 B, swizzled
__device__ __forceinline__ int haddr(int buf, int m, int k) {
  return buf + m * 1024 + ((k * 2) ^ ((m & 7) << 4));
}
// t1 region (aliases both h buffers): [64][1024] f16 rows of 2048 B, swizzled
__device__ __forceinline__ int taddr(int m, int c) {
  return m * 2048 + ((c * 2) ^ ((m & 7) << 4));
}

// ---------------------------------------------------------------------------
// Prologue: fp16 weights (K-contiguous) + pre-summed gate biases.
// ---------------------------------------------------------------------------
__global__ void cvt_weights(const float* __restrict__ W1, const float* __restrict__ W2,
                            const float* __restrict__ Whh, const float* __restrict__ Wo1,
                            const float* __restrict__ bih, const float* __restrict__ bhh,
                            f16* __restrict__ w1t, f16* __restrict__ w2t,
                            f16* __restrict__ whh, f16* __restrict__ wo1t,
                            float* __restrict__ bcr, float* __restrict__ bcz) {
  int i = blockIdx.x * 256 + threadIdx.x;
  if (i < 163840) { int n = i / 160; int k = i - n * 160; w1t[i] = (f16)W1[k * 1024 + n]; return; }
  i -= 163840;
  if (i < 524288) { int n = i >> 10; int k = i & 1023; w2t[i] = (f16)W2[k * 512 + n]; return; }
  i -= 524288;
  if (i < 786432) { whh[i] = (f16)Whh[i]; return; }
  i -= 786432;
  if (i < 131072) { int o = i >> 9; int k = i & 511; wo1t[i] = (f16)Wo1[k * 256 + o]; return; }
  i -= 131072;
  if (i < 512) { bcr[i] = bih[i] + bhh[i]; return; }
  i -= 512;
  if (i < 512) { bcz[i] = bih[512 + i] + bhh[512 + i]; return; }
}

// ---------------------------------------------------------------------------
// Main fused kernel: 1024 threads = 16 waves, 64 rows/block, 1 block/CU.
// __launch_bounds__(1024, 2): min-waves 2 -> allocator budget 128 VGPR
// (see R6 header note); occupancy is LDS-capped at 4 waves/SIMD anyway.
// ---------------------------------------------------------------------------
__global__ __launch_bounds__(1024, 2)
void gru_main(
    const float* __restrict__ zq, const float* __restrict__ fpr,
    const float* __restrict__ b1, const float* __restrict__ g1, const float* __restrict__ be1,
    const float* __restrict__ b2, const float* __restrict__ stok,
    const float* __restrict__ Wih, const float* __restrict__ bih, const float* __restrict__ bhh,
    const float* __restrict__ bo1, const float* __restrict__ go, const float* __restrict__ beo,
    const float* __restrict__ Wo2, const float* __restrict__ bo2,
    const f16* __restrict__ w1t, const f16* __restrict__ w2t,
    const f16* __restrict__ whh, const f16* __restrict__ wo1t,
    const float* __restrict__ bcr, const float* __restrict__ bcz,
    float* __restrict__ out) {
  __shared__ __align__(16) unsigned char sm[131072];  // h dbuf 2x[64][512] / t1[64][1024]
  __shared__ float sm_s[64 * 20], sm_ss[64 * 20], sm_yp[64 * 20];
  __shared__ float sm_x[64];

  const int tid = threadIdx.x;
  const int w = tid >> 6;        // 0..15
  const int lane = tid & 63;
  const int l16 = lane & 15;
  const int l4 = lane >> 4;
  const int R0 = blockIdx.x * 64;

  const float bo2v = bo2[0];
  if (tid < 64) sm_x[tid] = stok[0];

  // ================= G0a: t1 = cat(zq,fpr) @ W1 + b1 ======================
  #pragma unroll 1
  for (int q = 0; q < 4; ++q) {
    f32x4 acc[4];
    #pragma unroll
    for (int mt = 0; mt < 4; ++mt) acc[mt] = (f32x4){0.f, 0.f, 0.f, 0.f};
    #pragma unroll
    for (int kf = 0; kf < 5; ++kf) {
      const int k0 = kf * 32 + l4 * 8;
      f16x8 B[4];
      #pragma unroll
      for (int mt = 0; mt < 4; ++mt) {
        const int gm = R0 + mt * 16 + l16;
        const float* src = (kf < 4) ? (zq + gm * 128 + k0) : (fpr + gm * 32 + (k0 - 128));
        float4 v0 = *(const float4*)src;
        float4 v1 = *(const float4*)(src + 4);
        f16x8 b;
        b[0] = (f16)v0.x; b[1] = (f16)v0.y; b[2] = (f16)v0.z; b[3] = (f16)v0.w;
        b[4] = (f16)v1.x; b[5] = (f16)v1.y; b[6] = (f16)v1.z; b[7] = (f16)v1.w;
        B[mt] = b;
      }
      const f16x8 A = *(const f16x8*)(w1t + (w * 64 + q * 16 + l16) * 160 + k0);
      #pragma unroll
      for (int mt = 0; mt < 4; ++mt)
        acc[mt] = __builtin_amdgcn_mfma_f32_16x16x32_f16(A, B[mt], acc[mt], 0, 0, 0);
    }
    const int jq = w * 64 + q * 16 + l4 * 4;
    float bb[4]; st4(bb, *(const float4*)(b1 + jq));
    #pragma unroll
    for (int mt = 0; mt < 4; ++mt) {
      f16x4 v;
      #pragma unroll
      for (int r = 0; r < 4; ++r) v[r] = (f16)(acc[mt][r] + bb[r]);
      *(f16x4*)(sm + taddr(mt * 16 + l16, jq)) = v;
    }
  }
  __syncthreads();
  // ================= LN(1024) + GELU in place ==============================
  {
    const int m = tid >> 4;          // 0..63
    const int c0 = (tid & 15) * 64;  // 64-col strip
    float s = 0.f, ss = 0.f;
    #pragma unroll
    for (int cb = 0; cb < 8; ++cb) {
      f16x8 v = *(const f16x8*)(sm + taddr(m, c0 + cb * 8));
      #pragma unroll
      for (int i = 0; i < 8; ++i) { float f = (float)v[i]; s += f; ss += f * f; }
    }
    s += __shfl_xor(s, 1); ss += __shfl_xor(ss, 1);
    s += __shfl_xor(s, 2); ss += __shfl_xor(ss, 2);
    s += __shfl_xor(s, 4); ss += __shfl_xor(ss, 4);
    s += __shfl_xor(s, 8); ss += __shfl_xor(ss, 8);
    const float mean = s * (1.f / 1024.f);
    const float rstd = rsqrtf(ss * (1.f / 1024.f) - mean * mean + 1e-5f);
    #pragma unroll 2
    for (int cb = 0; cb < 8; ++cb) {
      const int c = c0 + cb * 8;
      f16x8 v = *(const f16x8*)(sm + taddr(m, c));
      float4 ga = *(const float4*)(g1 + c);
      float4 gb = *(const float4*)(g1 + c + 4);
      float4 ba = *(const float4*)(be1 + c);
      float4 bb = *(const float4*)(be1 + c + 4);
      float gs[8] = {ga.x, ga.y, ga.z, ga.w, gb.x, gb.y, gb.z, gb.w};
      float bs[8] = {ba.x, ba.y, ba.z, ba.w, bb.x, bb.y, bb.z, bb.w};
      f16x8 o;
      #pragma unroll
      for (int i = 0; i < 8; ++i)
        o[i] = (f16)gelu_e(((float)v[i] - mean) * rstd * gs[i] + bs[i]);
      *(f16x8*)(sm + taddr(m, c)) = o;
    }
  }
  __syncthreads();
  // ================= G0b: h0 = tanh(t1g @ W2 + b2) -> regs =================
  f16x4 h0[2][4];
  #pragma unroll 1
  for (int jh = 0; jh < 2; ++jh) {
    f32x4 acc[4];
    #pragma unroll
    for (int mt = 0; mt < 4; ++mt) acc[mt] = (f32x4){0.f, 0.f, 0.f, 0.f};
    #pragma unroll 2
    for (int kf = 0; kf < 32; ++kf) {
      const int k0 = kf * 32 + l4 * 8;
      f16x8 B[4];
      #pragma unroll
      for (int mt = 0; mt < 4; ++mt)
        B[mt] = *(const f16x8*)(sm + taddr(mt * 16 + l16, k0));
      const f16x8 A = *(const f16x8*)(w2t + (w * 32 + jh * 16 + l16) * 1024 + k0);
      #pragma unroll
      for (int mt = 0; mt < 4; ++mt)
        acc[mt] = __builtin_amdgcn_mfma_f32_16x16x32_f16(A, B[mt], acc[mt], 0, 0, 0);
    }
    const int jq = w * 32 + jh * 16 + l4 * 4;
    float bb[4]; st4(bb, *(const float4*)(b2 + jq));
    #pragma unroll
    for (int mt = 0; mt < 4; ++mt) {
      f16x4 v;
      #pragma unroll
      for (int r = 0; r < 4; ++r) v[r] = (f16)tanh_s(acc[mt][r] + bb[r]);
      h0[jh][mt] = v;
    }
  }
  __syncthreads();  // all t1 reads done; region reusable as h buffers
  #pragma unroll
  for (int jh = 0; jh < 2; ++jh) {
    const int jq = w * 32 + jh * 16 + l4 * 4;
    #pragma unroll
    for (int mt = 0; mt < 4; ++mt)
      *(f16x4*)(sm + haddr(0, mt * 16 + l16, jq)) = h0[jh][mt];
  }
  __syncthreads();

  // ============================ GRU loop ===================================
  #pragma unroll 1
  for (int t = 0; t < TSTEPS; ++t) {
    const int cur = (t & 1) << 16;
    const int nxt = cur ^ 65536;
    // ---- G1: gates = Whh · h^T, blend -> h[nxt] directly ------------------
    #pragma unroll 1
    for (int q = 0; q < 2; ++q) {
      const int jt = w * 32 + q * 16;
      f32x4 acc[4][3];
      #pragma unroll
      for (int mt = 0; mt < 4; ++mt)
        #pragma unroll
        for (int g = 0; g < 3; ++g) acc[mt][g] = (f32x4){0.f, 0.f, 0.f, 0.f};
      #pragma unroll 2
      for (int kf = 0; kf < 16; ++kf) {
        const int k0 = kf * 32 + l4 * 8;
        f16x8 B[4];
        #pragma unroll
        for (int mt = 0; mt < 4; ++mt)
          B[mt] = *(const f16x8*)(sm + haddr(cur, mt * 16 + l16, k0));
        #pragma unroll
        for (int g = 0; g < 3; ++g) {
          const f16x8 A = *(const f16x8*)(whh + (g * 512 + jt + l16) * 512 + k0);
          #pragma unroll
          for (int mt = 0; mt < 4; ++mt)
            acc[mt][g] = __builtin_amdgcn_mfma_f32_16x16x32_f16(A, B[mt], acc[mt][g], 0, 0, 0);
        }
      }
      if (q == 0) __syncthreads();  // B5: sm_x(t) visible (hidden behind q0 MFMA)
      const int jq = jt + l4 * 4;
      float wr[4], wz[4], wn[4], cr[4], cz[4], bn[4], cn[4];
      st4(wr, *(const float4*)(Wih + jq));
      st4(wz, *(const float4*)(Wih + 512 + jq));
      st4(wn, *(const float4*)(Wih + 1024 + jq));
      st4(cr, *(const float4*)(bcr + jq));
      st4(cz, *(const float4*)(bcz + jq));
      st4(bn, *(const float4*)(bih + 1024 + jq));
      st4(cn, *(const float4*)(bhh + 1024 + jq));
      #pragma unroll
      for (int mt = 0; mt < 4; ++mt) {
        const int m = mt * 16 + l16;
        const float x = sm_x[m];
        const int hoff = m * 1024 + ((jq * 2) ^ ((m & 7) << 4));
        const f16x4 ho = *(const f16x4*)(sm + cur + hoff);
        f16x4 hn;
        #pragma unroll
        for (int r = 0; r < 4; ++r) {
          const float gr = sigm(x * wr[r] + cr[r] + acc[mt][0][r]);
          const float gz = sigm(x * wz[r] + cz[r] + acc[mt][1][r]);
          const float gn = tanh_s(x * wn[r] + bn[r] + gr * (acc[mt][2][r] + cn[r]));
          hn[r] = (f16)((1.f - gz) * gn + gz * (float)ho[r]);
        }
        *(f16x4*)(sm + nxt + hoff) = hn;
      }
    }
    __syncthreads();  // B2: h[nxt] complete
    // ---- G2: y = gelu(LN(h_new @ Wo1 + bo1)) @ Wo2 + bo2 ------------------
    {
      f32x4 a2[4];
      #pragma unroll
      for (int mt = 0; mt < 4; ++mt) a2[mt] = (f32x4){0.f, 0.f, 0.f, 0.f};
      #pragma unroll 2
      for (int kf = 0; kf < 16; ++kf) {
        const int k0 = kf * 32 + l4 * 8;
        f16x8 B[4];
        #pragma unroll
        for (int mt = 0; mt < 4; ++mt)
          B[mt] = *(const f16x8*)(sm + haddr(nxt, mt * 16 + l16, k0));
        const f16x8 A = *(const f16x8*)(wo1t + (w * 16 + l16) * 512 + k0);
        #pragma unroll
        for (int mt = 0; mt < 4; ++mt)
          a2[mt] = __builtin_amdgcn_mfma_f32_16x16x32_f16(A, B[mt], a2[mt], 0, 0, 0);
      }
      const int c4 = w * 16 + l4 * 4;
      float vv[4][4];
      float bo1v[4]; st4(bo1v, *(const float4*)(bo1 + c4));
      #pragma unroll
      for (int mt = 0; mt < 4; ++mt) {
        float s = 0.f, ss = 0.f;
        #pragma unroll
        for (int r = 0; r < 4; ++r) {
          const float v = a2[mt][r] + bo1v[r];
          vv[mt][r] = v; s += v; ss += v * v;
        }
        s += __shfl_xor(s, 16); ss += __shfl_xor(ss, 16);
        s += __shfl_xor(s, 32); ss += __shfl_xor(ss, 32);
        if (l4 == 0) {
          const int m = mt * 16 + l16;
          sm_s[m * 20 + w] = s;
          sm_ss[m * 20 + w] = ss;
        }
      }
      __syncthreads();  // B3: stats partials visible
      float gov[4], bev[4], wv[4];
      st4(gov, *(const float4*)(go + c4));
      st4(bev, *(const float4*)(beo + c4));
      st4(wv, *(const float4*)(Wo2 + c4));
      #pragma unroll
      for (int mt = 0; mt < 4; ++mt) {
        const int m = mt * 16 + l16;
        float s = 0.f, ss = 0.f;
        #pragma unroll
        for (int i = 0; i < 4; ++i) {
          float4 ps = *(const float4*)(sm_s + m * 20 + i * 4);
          float4 pq = *(const float4*)(sm_ss + m * 20 + i * 4);
          s += ps.x + ps.y + ps.z + ps.w;
          ss += pq.x + pq.y + pq.z + pq.w;
        }
        const float mean = s * (1.f / 256.f);
        const float rstd = rsqrtf(ss * (1.f / 256.f) - mean * mean + 1e-5f);
        float y = 0.f;
        #pragma unroll
        for (int r = 0; r < 4; ++r)
          y += gelu_e((vv[mt][r] - mean) * rstd * gov[r] + bev[r]) * wv[r];
        y += __shfl_xor(y, 16);
        y += __shfl_xor(y, 32);
        if (l4 == 0) sm_yp[m * 20 + w] = y;
      }
      __syncthreads();  // B4: y partials visible
      if (tid < 64) {
        const int m = tid;
        float y = bo2v;
        #pragma unroll
        for (int i = 0; i < 4; ++i) {
          float4 ps = *(const float4*)(sm_yp + m * 20 + i * 4);
          y += ps.x + ps.y + ps.z + ps.w;
        }
        sm_x[m] = y;
        out[(R0 + m) * 20 + t] = y;
      }
      // no trailing barrier: next step's B5 (inside q0) covers sm_x visibility
    }
  }
}

// ---------------------------------------------------------------------------
extern "C" void kernel_launch(void* const* d_in, const int* in_sizes, int n_in,
                              void* d_out, int out_size, void* d_ws, size_t ws_size,
                              hipStream_t stream) {
  const float* zq   = (const float*)d_in[0];
  const float* fpr  = (const float*)d_in[1];
  const float* W1   = (const float*)d_in[2];
  const float* b1   = (const float*)d_in[3];
  const float* g1   = (const float*)d_in[4];
  const float* be1  = (const float*)d_in[5];
  const float* W2   = (const float*)d_in[6];
  const float* b2   = (const float*)d_in[7];
  const float* stok = (const float*)d_in[8];
  const float* Wih  = (const float*)d_in[9];
  const float* Whh  = (const float*)d_in[10];
  const float* bih  = (const float*)d_in[11];
  const float* bhh  = (const float*)d_in[12];
  const float* Wo1  = (const float*)d_in[13];
  const float* bo1  = (const float*)d_in[14];
  const float* go   = (const float*)d_in[15];
  const float* beo  = (const float*)d_in[16];
  const float* Wo2  = (const float*)d_in[17];
  const float* bo2  = (const float*)d_in[18];

  char* ws = (char*)d_ws;
  f16* w1t   = (f16*)(ws + 0);        // 1024*160*2  = 327680
  f16* w2t   = (f16*)(ws + 327680);   // 512*1024*2  = 1048576
  f16* whh   = (f16*)(ws + 1376256);  // 1536*512*2  = 1572864
  f16* wo1t  = (f16*)(ws + 2949120);  // 256*512*2   = 262144
  float* bcr = (float*)(ws + 3211264);  // 512*4 = 2048
  float* bcz = (float*)(ws + 3213312);  // 512*4 = 2048  (total ~3.2MB)

  cvt_weights<<<6276, 256, 0, stream>>>(W1, W2, Whh, Wo1, bih, bhh,
                                        w1t, w2t, whh, wo1t, bcr, bcz);

  const int N = in_sizes[0] / 128;  // 65536 rows
  gru_main<<<N / 64, 1024, 0, stream>>>(zq, fpr, b1, g1, be1, b2, stok, Wih, bih, bhh,
                                        bo1, go, beo, Wo2, bo2, w1t, w2t, whh, wo1t,
                                        bcr, bcz, (float*)d_out);
}